// Round 1
// baseline (301.195 us; speedup 1.0000x reference)
//
#include <hip/hip_runtime.h>

// PointPillarScatter on MI355X (gfx950)
// R5: NT stores -> plain streaming stores (fill kernels prove plain path
// sustains 6.4 TB/s; NT path suspected of capping write BW). Vectorized
// fill_map (int4) and scatter coords load (vint4).
#define GNX 512
#define GNY 512
#define GC  64

typedef float vfloat4 __attribute__((ext_vector_type(4)));
typedef int   vint4   __attribute__((ext_vector_type(4)));

// Step 0: fill cell->pillar map with -1, 16B per thread.
__global__ void pp_fill_map(vint4* __restrict__ map, int n4) {
    int i = blockIdx.x * blockDim.x + threadIdx.x;
    if (i < n4) {
        vint4 m1 = { -1, -1, -1, -1 };
        map[i] = m1;
    }
}

// Step 1: scatter pillar index p into dense (b, y, x) -> p map. coords int32.
__global__ void pp_scatter_idx(const vint4* __restrict__ coords,
                               int* __restrict__ map, int P) {
    int p = blockIdx.x * blockDim.x + threadIdx.x;
    if (p >= P) return;
    vint4 c = coords[p];                       // [b, z, y, x]
    map[c[0] * (GNY * GNX) + c[1] + c[2] * GNX + c[3]] = p;
}

// Step 2: channel-blocked gather. Thread = (x-quad, 8-channel group).
// fr[4][2] = 32 VGPRs -> 8 waves/SIMD for latency hiding of the
// map->feat dependent-load chain. Stores are PLAIN (cached) streaming
// stores: 268 MB streams through L2 like the 6.4 TB/s fill kernels;
// map (4 MiB) and feat (31 MB) stay L3-resident either way.
__global__ void __launch_bounds__(256) pp_gather_out(
        const float* __restrict__ feat, const int* __restrict__ map,
        float* __restrict__ out, int nquad) {
    int q  = blockIdx.x * blockDim.x + threadIdx.x;   // x-quad id
    if (q >= nquad) return;
    int cg = blockIdx.y;                              // channel group 0..7

    int x4 = q & (GNX / 4 - 1);        // x / 4
    int y  = (q >> 7) & (GNY - 1);
    int b  = q >> 16;

    int cellbase = (b << 18) + (y << 9) + (x4 << 2);
    vint4 m = *(const vint4*)(map + cellbase);

    vfloat4 fr[4][2];                  // [cell j][k] = channels cg*8+4k..+3
#pragma unroll
    for (int j = 0; j < 4; ++j) {
        fr[j][0] = (vfloat4)0.f;
        fr[j][1] = (vfloat4)0.f;
    }

#pragma unroll
    for (int j = 0; j < 4; ++j) {
        int pj = m[j];
        if (pj >= 0) {
            const vfloat4* fp = (const vfloat4*)(feat + (pj << 6) + (cg << 3));
            fr[j][0] = fp[0];
            fr[j][1] = fp[1];
        }
    }

    // store: channel w = 4k+t; plane stride 1<<18 floats
    int rowoff = (y << 9) + (x4 << 2);
    float* obase = out + (((b << 6) + (cg << 3)) << 18) + rowoff;
#pragma unroll
    for (int k = 0; k < 2; ++k) {
#pragma unroll
        for (int t = 0; t < 4; ++t) {
            vfloat4 v = { fr[0][k][t], fr[1][k][t], fr[2][k][t], fr[3][k][t] };
            *(vfloat4*)(obase + ((k * 4 + t) << 18)) = v;
        }
    }
}

extern "C" void kernel_launch(void* const* d_in, const int* in_sizes, int n_in,
                              void* d_out, int out_size, void* d_ws, size_t ws_size,
                              hipStream_t stream) {
    const float* feat   = (const float*)d_in[0];
    const int*   coords = (const int*)d_in[1];   // int32 (harness converts int64)
    int P = in_sizes[1] / 4;                     // 120000
    int B = out_size / (GC * GNY * GNX);         // 4 (floats per batch slice)
    int* map = (int*)d_ws;
    int mapN = B * GNY * GNX;                    // 1,048,576 ints (4 MiB)

    int n4 = mapN / 4;
    pp_fill_map<<<(n4 + 255) / 256, 256, 0, stream>>>((vint4*)map, n4);
    pp_scatter_idx<<<(P + 255) / 256, 256, 0, stream>>>(
        (const vint4*)coords, map, P);

    int nquad = B * GNY * (GNX / 4);             // 262,144 x-quads
    dim3 grid((nquad + 255) / 256, GC / 8, 1);   // y-dim = 8 channel groups
    pp_gather_out<<<grid, 256, 0, stream>>>(feat, map, (float*)d_out, nquad);
}

// Round 2
// 293.803 us; speedup vs baseline: 1.0252x; 1.0252x over previous
//
#include <hip/hip_runtime.h>

// PointPillarScatter on MI355X (gfx950)
// R6: revert to NT stores (R5 proved plain stores -7 us regression).
// Gather -> grid-stride persistent threads with 1-deep map prefetch:
// the map load for work item i+stride issues before processing item i,
// hiding the map->store dependent-load latency under the previous
// item's 8 NT stores. 2048 blocks x 256 thr, 4 work items/thread.
#define GNX 512
#define GNY 512
#define GC  64

typedef float vfloat4 __attribute__((ext_vector_type(4)));
typedef int   vint4   __attribute__((ext_vector_type(4)));

// Step 0: fill cell->pillar map with -1, 16B per thread.
__global__ void pp_fill_map(vint4* __restrict__ map, int n4) {
    int i = blockIdx.x * blockDim.x + threadIdx.x;
    if (i < n4) {
        vint4 m1 = { -1, -1, -1, -1 };
        map[i] = m1;
    }
}

// Step 1: scatter pillar index p into dense (b, y, x) -> p map. coords int32.
__global__ void pp_scatter_idx(const vint4* __restrict__ coords,
                               int* __restrict__ map, int P) {
    int p = blockIdx.x * blockDim.x + threadIdx.x;
    if (p >= P) return;
    vint4 c = coords[p];                       // [b, z, y, x]
    map[c[0] * (GNY * GNX) + c[1] + c[2] * GNX + c[3]] = p;
}

// Step 2: channel-blocked gather, grid-stride + software-pipelined map load.
// Work item w = cg * nquad + q; q -> (b, y, x4). fr[4][2] = 32 VGPRs.
// Stores NT (protect map/feat in L2 from the 268 MB output stream).
__global__ void __launch_bounds__(256) pp_gather_out(
        const float* __restrict__ feat, const int* __restrict__ map,
        float* __restrict__ out, int nwork, int nqlog) {
    int idx    = blockIdx.x * blockDim.x + threadIdx.x;
    int stride = gridDim.x * blockDim.x;
    if (idx >= nwork) return;

    int qmask = (1 << nqlog) - 1;

    // prologue: map load for first work item
    int w  = idx;
    int qq = w & qmask;
    int x4 = qq & (GNX / 4 - 1);
    int y  = (qq >> 7) & (GNY - 1);
    int b  = qq >> 16;
    vint4 m = *(const vint4*)(map + (b << 18) + (y << 9) + (x4 << 2));

    while (true) {
        // prefetch map for next work item (independent of current stores)
        int wn = w + stride;
        bool more = wn < nwork;
        vint4 mn = { -1, -1, -1, -1 };
        int x4n = 0, yn = 0, bn = 0;
        if (more) {
            int qn = wn & qmask;
            x4n = qn & (GNX / 4 - 1);
            yn  = (qn >> 7) & (GNY - 1);
            bn  = qn >> 16;
            mn = *(const vint4*)(map + (bn << 18) + (yn << 9) + (x4n << 2));
        }

        // process current work item
        int cg = w >> nqlog;                   // channel group 0..7
        vfloat4 fr[4][2];                      // [cell j][k] = ch cg*8+4k..+3
#pragma unroll
        for (int j = 0; j < 4; ++j) {
            fr[j][0] = (vfloat4)0.f;
            fr[j][1] = (vfloat4)0.f;
        }
#pragma unroll
        for (int j = 0; j < 4; ++j) {
            int pj = m[j];
            if (pj >= 0) {
                const vfloat4* fp = (const vfloat4*)(feat + (pj << 6) + (cg << 3));
                fr[j][0] = fp[0];
                fr[j][1] = fp[1];
            }
        }

        int rowoff = (y << 9) + (x4 << 2);
        float* obase = out + (((b << 6) + (cg << 3)) << 18) + rowoff;
#pragma unroll
        for (int k = 0; k < 2; ++k) {
#pragma unroll
            for (int t = 0; t < 4; ++t) {
                vfloat4 v = { fr[0][k][t], fr[1][k][t], fr[2][k][t], fr[3][k][t] };
                __builtin_nontemporal_store(v, (vfloat4*)(obase + ((k * 4 + t) << 18)));
            }
        }

        if (!more) break;
        w = wn; m = mn; x4 = x4n; y = yn; b = bn;
    }
}

extern "C" void kernel_launch(void* const* d_in, const int* in_sizes, int n_in,
                              void* d_out, int out_size, void* d_ws, size_t ws_size,
                              hipStream_t stream) {
    const float* feat   = (const float*)d_in[0];
    const int*   coords = (const int*)d_in[1];   // int32 (harness converts int64)
    int P = in_sizes[1] / 4;                     // 120000
    int B = out_size / (GC * GNY * GNX);         // 4
    int* map = (int*)d_ws;
    int mapN = B * GNY * GNX;                    // 1,048,576 ints (4 MiB)

    int n4 = mapN / 4;
    pp_fill_map<<<(n4 + 255) / 256, 256, 0, stream>>>((vint4*)map, n4);
    pp_scatter_idx<<<(P + 255) / 256, 256, 0, stream>>>(
        (const vint4*)coords, map, P);

    int nquad = B * GNY * (GNX / 4);             // 262,144 x-quads
    int nwork = nquad * (GC / 8);                // 2,097,152 work items
    int nqlog = 31 - __builtin_clz((unsigned)nquad);  // 18
    // 2048 blocks = 8 blocks/CU target; 4 work items per thread.
    pp_gather_out<<<2048, 256, 0, stream>>>(feat, map, (float*)d_out,
                                            nwork, nqlog);
}